// Round 6
// baseline (417.277 us; speedup 1.0000x reference)
//
#include <hip/hip_runtime.h>

// EGA layer (GAT-like, GLOBAL per-head softmax over edges) on MI355X.
// Round 6:
//  - scores via associativity s = x·(W·a) + b·a  (exact f32, fused into split
//    kernel) -> gemm epilogue stores ONLY Wh
//  - Wh stored bf16 (halves write + scatter fetch; +~2e-3 abs error, ok)
//  - gemm K-loop software-pipelined (next tile loads overlap MFMA)
//  - R5 keepers: XCD swizzle, LDS-staged coalesced epilogue, bf16x3 split GEMM
//
// R5 post-mortem: gemm was write-bound (418MB HBM writes for 106MB logical,
// ~4x amplification, all pipes <30%). This round minimizes + uniformizes the
// gemm store stream to isolate and shrink it.

#define N_NODES  50000
#define N_EDGES  800000
#define IN_DIM   256
#define OUT_DIM  64
#define HEADS    8
#define NCOL     512
#define KP       768                 // split K' = 3*256
#define NBLK_RED 1024
#define LN_W_EPS (-20.72326584f)     // ln(1e-9) skip threshold
#define NRB      391                 // ceil(50000/128) row blocks

typedef __bf16 bf16x8 __attribute__((ext_vector_type(8)));
typedef float  f32x4  __attribute__((ext_vector_type(4)));

__device__ __forceinline__ short f2bf(float f) {     // RNE float->bf16 bits
    unsigned u = __builtin_bit_cast(unsigned, f);
    u += 0x7fffu + ((u >> 16) & 1u);
    return (short)(u >> 16);
}
__device__ __forceinline__ float bf2f(short s) {
    unsigned u = ((unsigned)(unsigned short)s) << 16;
    return __builtin_bit_cast(float, u);
}
__device__ __forceinline__ int pack2(short a, short b) {
    return (int)((unsigned short)a | ((unsigned)(unsigned short)b << 16));
}

// ---------------------------------------------------------------------------
// Bt[n][k'] (n-major, 512 x 768 bf16): rows of B' = [Wh; Wh; Wl]
// ---------------------------------------------------------------------------
__global__ void wprep_kernel(const float* __restrict__ W, short* __restrict__ Bt)
{
    const int g = blockIdx.x * 256 + threadIdx.x;   // 512*256 exact
    const int n = g >> 8, d = g & 255;
    const int h = n >> 6, o = n & 63;
    const float w = W[((size_t)h * IN_DIM + d) * OUT_DIM + o];
    const short hi = f2bf(w);
    const short lo = f2bf(w - bf2f(hi));
    Bt[(size_t)n * KP + d]       = hi;
    Bt[(size_t)n * KP + 256 + d] = hi;
    Bt[(size_t)n * KP + 512 + d] = lo;
}

// ---------------------------------------------------------------------------
// vbuf: [0:2048) v_src[h][d]=W[h][:,d]... = sum_o W[h][d][o]*a[h][o]
//       [2048:4096) v_dst (a offset 64); [4096:4104) c_src=b·a_src;
//       [4104:4112) c_dst.
// ---------------------------------------------------------------------------
__global__ void vprep_kernel(const float* __restrict__ W,
                             const float* __restrict__ a,
                             const float* __restrict__ b,
                             float* __restrict__ vbuf)
{
    const int g = blockIdx.x * 256 + threadIdx.x;
    if (g < 4096) {
        const int dst = g & 2047;
        const int h = dst >> 8, d = dst & 255;
        const float* wp = W + ((size_t)h * IN_DIM + d) * OUT_DIM;
        const float* ap = a + h * 128 + ((g < 2048) ? 0 : 64);
        float sum = 0.f;
        for (int o = 0; o < 64; ++o) sum += wp[o] * ap[o];
        vbuf[g] = sum;
    } else if (g < 4112) {
        const int h = (g - 4096) & 7;
        const float* ap = a + h * 128 + ((g < 4104) ? 0 : 64);
        const float* bp = b + h * 64;
        float sum = 0.f;
        for (int o = 0; o < 64; ++o) sum += bp[o] * ap[o];
        vbuf[g] = sum;
    }
}

// ---------------------------------------------------------------------------
// Fused split + exact-f32 scores. One wave per row (grid-stride);
// per-thread v cache (16 float4) loaded once.
// ---------------------------------------------------------------------------
__global__ __launch_bounds__(256) void split_score_kernel(
    const float* __restrict__ x, const float* __restrict__ vbuf,
    short* __restrict__ A2, float* __restrict__ s_src, float* __restrict__ s_dst)
{
    const int lane = threadIdx.x & 63;
    const int gw   = (int)((blockIdx.x * 256 + threadIdx.x) >> 6);
    const int nw   = (int)((gridDim.x * 256) >> 6);

    float4 vs[8], vd[8];
    #pragma unroll
    for (int h = 0; h < 8; ++h) {
        vs[h] = *(const float4*)(vbuf + h * 256 + lane * 4);
        vd[h] = *(const float4*)(vbuf + 2048 + h * 256 + lane * 4);
    }

    for (int row = gw; row < N_NODES; row += nw) {
        const float4 v = *(const float4*)(x + (size_t)row * IN_DIM + lane * 4);
        short4 hi, lo;
        hi.x = f2bf(v.x); lo.x = f2bf(v.x - bf2f(hi.x));
        hi.y = f2bf(v.y); lo.y = f2bf(v.y - bf2f(hi.y));
        hi.z = f2bf(v.z); lo.z = f2bf(v.z - bf2f(hi.z));
        hi.w = f2bf(v.w); lo.w = f2bf(v.w - bf2f(hi.w));
        *(short4*)(A2 + (size_t)row * 512 + lane * 4)       = hi;
        *(short4*)(A2 + (size_t)row * 512 + 256 + lane * 4) = lo;

        #pragma unroll
        for (int h = 0; h < 8; ++h) {
            float ps = v.x * vs[h].x + v.y * vs[h].y + v.z * vs[h].z + v.w * vs[h].w;
            float pd = v.x * vd[h].x + v.y * vd[h].y + v.z * vd[h].z + v.w * vd[h].w;
            #pragma unroll
            for (int off = 32; off; off >>= 1) {
                ps += __shfl_down(ps, off);
                pd += __shfl_down(pd, off);
            }
            if (lane == 0) {
                s_src[row * 8 + h] = ps + vbuf[4096 + h];
                s_dst[row * 8 + h] = pd + vbuf[4104 + h];
            }
        }
    }
}

// ---------------------------------------------------------------------------
// MFMA GEMM, 128x128 tile, BK=64, 16x16x32 bf16, software-pipelined K-loop.
// Epilogue: acc+bias -> LDS f32 stage -> coalesced bf16 row stores (256B/row).
// ---------------------------------------------------------------------------
__global__ __launch_bounds__(256) void gemm_kernel(
    const short* __restrict__ A2, const short* __restrict__ Bt,
    const float* __restrict__ b, unsigned short* __restrict__ Whb)
{
    __shared__ __align__(16) char smem[36864];
    short* As    = (short*)smem;                 // 128*72 shorts
    short* Bs    = (short*)(smem + 18432);       // 128*72 shorts
    float* stage = (float*)smem;                 // 32*132 floats (epilogue)

    // XCD swizzle: all 4 n-blocks of a row panel on one XCD
    const int bid = blockIdx.x;
    const int xcd = bid & 7, q = bid >> 3;
    const int nb = q & 3;
    const int rb = (q >> 2) * 8 + xcd;
    if (rb >= NRB) return;
    const int row0 = rb * 128;
    const int n0   = nb * 128;

    const int tid  = threadIdx.x;
    const int wave = tid >> 6, lane = tid & 63;
    const int wm = wave >> 1, wn = wave & 1;
    const int cl = lane & 15, quad = lane >> 4;

    f32x4 acc[4][4] = {};
    int4 av[4], bv[4];

    // preload k0 = 0
    {
        const int ka = 0;
        #pragma unroll
        for (int t = 0; t < 4; ++t) {
            const int c  = tid + t * 256;
            const int r  = c >> 3;
            const int o8 = (c & 7) * 8;
            int ra = row0 + r; if (ra > N_NODES - 1) ra = N_NODES - 1;
            av[t] = *(const int4*)(A2 + (size_t)ra * 512 + ka + o8);
            bv[t] = *(const int4*)(Bt + (size_t)(n0 + r) * KP + 0 + o8);
        }
    }

    for (int k0 = 0; k0 < KP; k0 += 64) {
        __syncthreads();                         // prior LDS reads complete
        #pragma unroll
        for (int t = 0; t < 4; ++t) {
            const int c  = tid + t * 256;
            const int r  = c >> 3;
            const int o8 = (c & 7) * 8;
            *(int4*)(&As[r * 72 + o8]) = av[t];
            *(int4*)(&Bs[r * 72 + o8]) = bv[t];
        }
        __syncthreads();

        const int kn = k0 + 64;
        if (kn < KP) {                           // prefetch next tile (overlaps MFMA)
            const int ka = (kn < 512) ? kn : kn - 512;
            #pragma unroll
            for (int t = 0; t < 4; ++t) {
                const int c  = tid + t * 256;
                const int r  = c >> 3;
                const int o8 = (c & 7) * 8;
                int ra = row0 + r; if (ra > N_NODES - 1) ra = N_NODES - 1;
                av[t] = *(const int4*)(A2 + (size_t)ra * 512 + ka + o8);
                bv[t] = *(const int4*)(Bt + (size_t)(n0 + r) * KP + kn + o8);
            }
        }

        #pragma unroll
        for (int ks = 0; ks < 64; ks += 32) {
            bf16x8 af[4], bf[4];
            #pragma unroll
            for (int i = 0; i < 4; ++i)
                af[i] = *(const bf16x8*)(&As[(wm * 64 + i * 16 + cl) * 72 + ks + quad * 8]);
            #pragma unroll
            for (int j = 0; j < 4; ++j)
                bf[j] = *(const bf16x8*)(&Bs[(wn * 64 + j * 16 + cl) * 72 + ks + quad * 8]);
            #pragma unroll
            for (int i = 0; i < 4; ++i)
                #pragma unroll
                for (int j = 0; j < 4; ++j)
                    acc[i][j] = __builtin_amdgcn_mfma_f32_16x16x32_bf16(
                        af[i], bf[j], acc[i][j], 0, 0, 0);
        }
    }

    // Epilogue: only Wh (bf16). C/D: col=lane&15, row=quad*4+r.
    float bsv[4];
    #pragma unroll
    for (int j = 0; j < 4; ++j)
        bsv[j] = b[n0 + wn * 64 + j * 16 + cl];

    #pragma unroll
    for (int i = 0; i < 4; ++i) {
        __syncthreads();
        #pragma unroll
        for (int r = 0; r < 4; ++r)
            #pragma unroll
            for (int j = 0; j < 4; ++j)
                stage[(wm * 16 + quad * 4 + r) * 132 + wn * 64 + j * 16 + cl] =
                    acc[i][j][r] + bsv[j];
        __syncthreads();
        // coalesced bf16 store: 32 rows x 128 cols, 256B contiguous per row
        #pragma unroll
        for (int s = 0; s < 2; ++s) {
            const int idx  = tid + s * 256;     // 0..511
            const int lrow = idx >> 4;          // 0..31
            const int ch   = idx & 15;          // 8-col chunk
            const int grow = row0 + (lrow >> 4) * 64 + i * 16 + (lrow & 15);
            if (grow < N_NODES) {
                const float* sp = stage + lrow * 132 + ch * 8;
                int4 o;
                o.x = pack2(f2bf(sp[0]), f2bf(sp[1]));
                o.y = pack2(f2bf(sp[2]), f2bf(sp[3]));
                o.z = pack2(f2bf(sp[4]), f2bf(sp[5]));
                o.w = pack2(f2bf(sp[6]), f2bf(sp[7]));
                *(int4*)(Whb + (size_t)grow * NCOL + n0 + ch * 8) = o;
            }
        }
    }
}

// ---------------------------------------------------------------------------
// Online (max, sumexp) over all edges per head. Per-block partials.
// ---------------------------------------------------------------------------
__global__ __launch_bounds__(256) void edge_reduce_kernel(
    const int* __restrict__ ei, const float* __restrict__ s_src,
    const float* __restrict__ s_dst, float* __restrict__ partial)
{
    float m[8], l[8];
    #pragma unroll
    for (int h = 0; h < 8; ++h) { m[h] = -1e30f; l[h] = 0.f; }

    for (int e = blockIdx.x * 256 + threadIdx.x; e < N_EDGES; e += gridDim.x * 256) {
        const int row = ei[e];
        const int col = ei[N_EDGES + e];
        const float4 s0 = *(const float4*)(s_src + row * 8);
        const float4 s1 = *(const float4*)(s_src + row * 8 + 4);
        const float4 d0 = *(const float4*)(s_dst + col * 8);
        const float4 d1 = *(const float4*)(s_dst + col * 8 + 4);
        const float ev[8] = { s0.x + d0.x, s0.y + d0.y, s0.z + d0.z, s0.w + d0.w,
                              s1.x + d1.x, s1.y + d1.y, s1.z + d1.z, s1.w + d1.w };
        #pragma unroll
        for (int h = 0; h < 8; ++h) {
            float t = ev[h];
            t = t > 0.f ? t : 0.01f * t;     // leaky_relu 0.01
            if (t > m[h]) { l[h] = l[h] * __expf(m[h] - t) + 1.f; m[h] = t; }
            else          { l[h] += __expf(t - m[h]); }
        }
    }

    __shared__ float red[16][256];
    const int tid = threadIdx.x;
    #pragma unroll
    for (int h = 0; h < 8; ++h) { red[h][tid] = m[h]; red[8 + h][tid] = l[h]; }
    __syncthreads();
    for (int s = 128; s > 0; s >>= 1) {
        if (tid < s) {
            #pragma unroll
            for (int h = 0; h < 8; ++h) {
                float mo = red[h][tid + s], lo = red[8 + h][tid + s];
                float mm = red[h][tid],     ll = red[8 + h][tid];
                if (mo > mm) { ll = ll * __expf(mm - mo) + lo; mm = mo; }
                else         { ll += lo * __expf(mo - mm); }
                red[h][tid] = mm; red[8 + h][tid] = ll;
            }
        }
        __syncthreads();
    }
    if (tid == 0) {
        #pragma unroll
        for (int h = 0; h < 8; ++h) {
            partial[blockIdx.x * 16 + h]     = red[h][0];
            partial[blockIdx.x * 16 + 8 + h] = red[8 + h][0];
        }
    }
}

// ---------------------------------------------------------------------------
// Merge partials. coef[h]=M_h, coef[8+h]=g_h/L_h, coef[16+h]=skip cutoff.
// ---------------------------------------------------------------------------
__global__ void finalize_kernel(const float* __restrict__ partial,
                                const float* __restrict__ gate,
                                float* __restrict__ coef, int nblk)
{
    const int t = threadIdx.x;           // 64 threads: h = t&7, chunk j = t>>3
    const int h = t & 7;
    const int j = t >> 3;
    float m = -1e30f, l = 0.f;
    for (int bk = j; bk < nblk; bk += 8) {
        const float mb = partial[bk * 16 + h];
        const float lb = partial[bk * 16 + 8 + h];
        if (mb > m) { l = l * __expf(m - mb) + lb; m = mb; }
        else        { l += lb * __expf(mb - m); }
    }
    #pragma unroll
    for (int s = 8; s < 64; s <<= 1) {
        const float mo = __shfl_xor(m, s);
        const float lo = __shfl_xor(l, s);
        if (mo > m) { l = l * __expf(m - mo) + lo; m = mo; }
        else        { l += lo * __expf(mo - m); }
    }
    if (j == 0) {
        float gm = gate[0];
        for (int i = 1; i < 8; ++i) gm = fmaxf(gm, gate[i]);
        float gs = 0.f;
        for (int i = 0; i < 8; ++i) gs += __expf(gate[i] - gm);
        const float g = __expf(gate[h] - gm) / gs;
        const float C = g / l;
        coef[h]      = m;
        coef[8 + h]  = C;
        coef[16 + h] = m + LN_W_EPS - __logf(C);   // t >= cut  <=>  w >= eps
    }
}

// ---------------------------------------------------------------------------
// Thresholded ballot scatter over bf16 Wh.
// ---------------------------------------------------------------------------
__global__ __launch_bounds__(256) void scatter_kernel(
    const int* __restrict__ ei, const float* __restrict__ s_src,
    const float* __restrict__ s_dst, const unsigned short* __restrict__ Whb,
    const float* __restrict__ coef, float* __restrict__ out)
{
    __shared__ float cM[8], cC[8], cCut[8];
    if (threadIdx.x < 8)       cM[threadIdx.x]        = coef[threadIdx.x];
    else if (threadIdx.x < 16) cC[threadIdx.x - 8]    = coef[threadIdx.x];
    else if (threadIdx.x < 24) cCut[threadIdx.x - 16] = coef[threadIdx.x];
    __syncthreads();

    const int lane = threadIdx.x & 63;
    const int e    = blockIdx.x * 256 + threadIdx.x;   // 800000/256 exact

    const int row = ei[e];
    const int col = ei[N_EDGES + e];
    const float4 s0 = *(const float4*)(s_src + row * 8);
    const float4 s1 = *(const float4*)(s_src + row * 8 + 4);
    const float4 d0 = *(const float4*)(s_dst + col * 8);
    const float4 d1 = *(const float4*)(s_dst + col * 8 + 4);
    float t[8] = { s0.x + d0.x, s0.y + d0.y, s0.z + d0.z, s0.w + d0.w,
                   s1.x + d1.x, s1.y + d1.y, s1.z + d1.z, s1.w + d1.w };
    bool pass = false;
    float w[8];
    #pragma unroll
    for (int h = 0; h < 8; ++h) {
        t[h] = t[h] > 0.f ? t[h] : 0.01f * t[h];
        pass |= (t[h] >= cCut[h]);
    }
    if (pass) {
        #pragma unroll
        for (int h = 0; h < 8; ++h)
            w[h] = __expf(t[h] - cM[h]) * cC[h];
    }

    unsigned long long mask = __ballot(pass);
    while (mask) {
        const int src = (int)__builtin_ctzll(mask);
        mask &= mask - 1;
        const int rb = __shfl(row, src);
        const int cb = __shfl(col, src);
        const unsigned short* wc = Whb + (size_t)cb * NCOL + lane;
        float acc = 0.f;
        #pragma unroll
        for (int h = 0; h < 8; ++h)
            acc += __shfl(w[h], src) * bf2f((short)wc[h * 64]);
        atomicAdd(out + (size_t)rb * OUT_DIM + lane, acc);
    }
}

// ---------------------------------------------------------------------------
extern "C" void kernel_launch(void* const* d_in, const int* in_sizes, int n_in,
                              void* d_out, int out_size, void* d_ws, size_t ws_size,
                              hipStream_t stream)
{
    const float* x    = (const float*)d_in[0];
    const int*   ei   = (const int*)  d_in[1];
    const float* W    = (const float*)d_in[2];
    const float* b    = (const float*)d_in[3];
    const float* a    = (const float*)d_in[4];
    const float* gate = (const float*)d_in[5];
    float* out = (float*)d_out;

    // workspace layout (bytes, 16B-aligned), total ~106.5 MB
    char* wsb = (char*)d_ws;
    short*          A2      = (short*)         (wsb);              // 51,200,000
    unsigned short* Whb     = (unsigned short*)(wsb + 51200000);   // 51,200,000
    short*          Bt      = (short*)         (wsb + 102400000);  // 786,432
    float*          vbuf    = (float*)         (wsb + 103186432);  // 16,448
    float*          s_src   = (float*)         (wsb + 103202880);  // 1,600,000
    float*          s_dst   = (float*)         (wsb + 104802880);  // 1,600,000
    float*          partial = (float*)         (wsb + 106402880);  // 65,536
    float*          coef    = (float*)         (wsb + 106468416);  // 128

    hipMemsetAsync(d_out, 0, (size_t)N_NODES * OUT_DIM * sizeof(float), stream);

    wprep_kernel<<<512, 256, 0, stream>>>(W, Bt);
    vprep_kernel<<<17, 256, 0, stream>>>(W, a, b, vbuf);

    split_score_kernel<<<2048, 256, 0, stream>>>(x, vbuf, A2, s_src, s_dst);

    gemm_kernel<<<8 * 4 * ((NRB + 7) / 8), 256, 0, stream>>>(A2, Bt, b, Whb);

    edge_reduce_kernel<<<NBLK_RED, 256, 0, stream>>>(ei, s_src, s_dst, partial);
    finalize_kernel<<<1, 64, 0, stream>>>(partial, gate, coef, NBLK_RED);

    scatter_kernel<<<N_EDGES / 256, 256, 0, stream>>>(
        ei, s_src, s_dst, Whb, coef, out);
}